// Round 4
// baseline (308.606 us; speedup 1.0000x reference)
//
#include <hip/hip_runtime.h>
#include <hip/hip_fp16.h>
#include <stdint.h>

#define LOG2_HASHMAP_SIZE 19
#define HASHMAP_SIZE (1u << LOG2_HASHMAP_SIZE)
#define HASHMAP_MASK (HASHMAP_SIZE - 1u)
#define N_LEVELS 4

// Level 0: res=30 -> 31 vertices per axis. Dense grid fits in LDS as half2.
#define R0 31
#define DENSE0_N (R0 * R0 * R0)        // 29791 vertices
#define DENSE0_BYTES (DENSE0_N * 4)    // half2 per vertex = 119164 B < 160 KiB

// native vector types usable with __builtin_nontemporal_*
typedef float v4f __attribute__((ext_vector_type(4)));
typedef float v2f __attribute__((ext_vector_type(2)));

__device__ __forceinline__ uint32_t hash3(uint32_t ix, uint32_t iy, uint32_t iz) {
    return (ix ^ (iy * 11614769u) ^ (iz * 2654435761u)) & HASHMAP_MASK;
}

// ---------------- fp32 path (fallback only) ----------------
__device__ __forceinline__ float2 level_embed_p(float px, float py, float pz,
                                                const float* __restrict__ tables,
                                                int li, float r)
{
    const uint32_t P1 = 11614769u;
    const uint32_t P2 = 2654435761u;

    const float sx = px * r, sy = py * r, sz = pz * r;
    const float bx = floorf(sx), by = floorf(sy), bz = floorf(sz);
    const float tx = sx - bx, ty = sy - by, tz = sz - bz;
    const float ux = 1.0f - tx, uy = 1.0f - ty, uz = 1.0f - tz;

    const uint32_t ix = (uint32_t)(int)bx;
    const uint32_t iy = (uint32_t)(int)by;
    const uint32_t iz = (uint32_t)(int)bz;

    const uint32_t hy0 = iy * P1, hy1 = (iy + 1u) * P1;
    const uint32_t hz0 = iz * P2, hz1 = (iz + 1u) * P2;

    uint32_t S[4];
    float W[4];
    S[0] = hy0 ^ hz0;  W[0] = uy * uz;
    S[1] = hy0 ^ hz1;  W[1] = uy * tz;
    S[2] = hy1 ^ hz0;  W[2] = ty * uz;
    S[3] = hy1 ^ hz1;  W[3] = ty * tz;

    const float* tab = tables + (size_t)li * HASHMAP_SIZE * 2;
    const float2* __restrict__ tab2 = (const float2*)tab;

    float f0 = 0.0f, f1 = 0.0f;
    #pragma unroll
    for (int c = 0; c < 4; ++c) {
        const uint32_t h0 = (ix ^ S[c]) & HASHMAP_MASK;
        const uint32_t h1 = ((ix + 1u) ^ S[c]) & HASHMAP_MASK;
        const float2 e0 = tab2[h0];
        const float2 e1 = tab2[h1];
        f0 += W[c] * (ux * e0.x + tx * e1.x);
        f1 += W[c] * (ux * e0.y + tx * e1.y);
    }
    return make_float2(f0, f1);
}

// ---------------- branch-free fp16 gather path ----------------
// Compute 8 corner hash indices + 8 trilinear weights. No even/odd branch:
// 8 independent 4B loads per point-level; the even-ix x-pair lands in one
// cache line and merges in L1/MSHR, so average distinct lines is unchanged
// while issue is divergence-free and fully pipelineable.
__device__ __forceinline__ void prep_level(float px, float py, float pz, float r,
                                           uint32_t* __restrict__ h,
                                           float* __restrict__ w)
{
    const uint32_t P1 = 11614769u;
    const uint32_t P2 = 2654435761u;

    const float sx = px * r, sy = py * r, sz = pz * r;
    const float bx = floorf(sx), by = floorf(sy), bz = floorf(sz);
    const float tx = sx - bx, ty = sy - by, tz = sz - bz;
    const float ux = 1.0f - tx, uy = 1.0f - ty, uz = 1.0f - tz;

    const uint32_t ix = (uint32_t)(int)bx;
    const uint32_t iy = (uint32_t)(int)by;
    const uint32_t iz = (uint32_t)(int)bz;

    const uint32_t hy0 = iy * P1, hy1 = (iy + 1u) * P1;
    const uint32_t hz0 = iz * P2, hz1 = (iz + 1u) * P2;

    const uint32_t S0 = hy0 ^ hz0, S1 = hy0 ^ hz1, S2 = hy1 ^ hz0, S3 = hy1 ^ hz1;
    const float W0 = uy * uz, W1 = uy * tz, W2 = ty * uz, W3 = ty * tz;

    const uint32_t ix1 = ix + 1u;
    h[0] = (ix  ^ S0) & HASHMAP_MASK;  w[0] = W0 * ux;
    h[1] = (ix1 ^ S0) & HASHMAP_MASK;  w[1] = W0 * tx;
    h[2] = (ix  ^ S1) & HASHMAP_MASK;  w[2] = W1 * ux;
    h[3] = (ix1 ^ S1) & HASHMAP_MASK;  w[3] = W1 * tx;
    h[4] = (ix  ^ S2) & HASHMAP_MASK;  w[4] = W2 * ux;
    h[5] = (ix1 ^ S2) & HASHMAP_MASK;  w[5] = W2 * tx;
    h[6] = (ix  ^ S3) & HASHMAP_MASK;  w[6] = W3 * ux;
    h[7] = (ix1 ^ S3) & HASHMAP_MASK;  w[7] = W3 * tx;
}

__device__ __forceinline__ float2 accum8(const uint32_t* __restrict__ v,
                                         const float* __restrict__ w)
{
    float f0 = 0.0f, f1 = 0.0f;
    #pragma unroll
    for (int j = 0; j < 8; ++j) {
        const uint32_t pj = v[j];
        const float2 e = __half22float2(*(const __half2*)&pj);
        f0 += w[j] * e.x;
        f1 += w[j] * e.y;
    }
    return make_float2(f0, f1);
}

// Setup 1: pack levels 1..3 tables to fp16 (half2 per entry) into ws.
__global__ __launch_bounds__(256) void convert_fp16(
    const float* __restrict__ tables, uint32_t* __restrict__ t16)
{
    const int i = blockIdx.x * blockDim.x + threadIdx.x;
    if (i >= 3 * (int)HASHMAP_SIZE) return;
    const float2 e = ((const float2*)tables)[HASHMAP_SIZE + i];  // levels 1..3 contiguous
    const __half2 p = __floats2half2_rn(e.x, e.y);
    t16[i] = *(const uint32_t*)&p;
}

// Setup 2: materialize level-0 dense vertex grid as half2.
__global__ __launch_bounds__(256) void build_dense0(
    const float* __restrict__ tables, uint32_t* __restrict__ dense0)
{
    const int v = blockIdx.x * blockDim.x + threadIdx.x;
    if (v >= DENSE0_N) return;
    const int vx = v / (R0 * R0);
    const int rem = v - vx * (R0 * R0);
    const int vy = rem / R0;
    const int vz = rem - vy * R0;
    const uint32_t h = hash3((uint32_t)vx, (uint32_t)vy, (uint32_t)vz);
    const float2 e = ((const float2*)tables)[h];   // level-0 table at offset 0
    const __half2 p = __floats2half2_rn(e.x, e.y);
    dense0[v] = *(const uint32_t*)&p;
}

// Gather pass for levels 1,2: one fp16 table (2 MB, L2-resident) per launch.
// 2 points per thread: 16 independent gather loads in flight per lane before
// any consumption -> ~2.7x the in-flight lines of the divergent version.
__global__ __launch_bounds__(256) void pass16_kernel(
    const float* __restrict__ x, const uint32_t* __restrict__ t16,
    float* __restrict__ ws, float r, int n)
{
    const size_t i0 = ((size_t)blockIdx.x * 256 + threadIdx.x) * 2;
    if (i0 + 2 <= (size_t)n) {
        const v2f* xv = (const v2f*)(x + 3 * i0);   // 24B per thread, 8B aligned
        const v2f a = __builtin_nontemporal_load(xv);
        const v2f b = __builtin_nontemporal_load(xv + 1);
        const v2f c = __builtin_nontemporal_load(xv + 2);

        uint32_t hA[8], hB[8];
        float wA[8], wB[8];
        prep_level(a.x, a.y, b.x, r, hA, wA);       // point i0
        prep_level(b.y, c.x, c.y, r, hB, wB);       // point i0+1

        uint32_t vA[8], vB[8];
        #pragma unroll
        for (int j = 0; j < 8; ++j) vA[j] = t16[hA[j]];
        #pragma unroll
        for (int j = 0; j < 8; ++j) vB[j] = t16[hB[j]];

        const float2 eA = accum8(vA, wA);
        const float2 eB = accum8(vB, wB);
        v4f o = {eA.x, eA.y, eB.x, eB.y};
        __builtin_nontemporal_store(o, (v4f*)(ws + 2 * i0));
    } else {
        for (size_t i = i0; i < (size_t)n; ++i) {
            const float px = x[3 * i + 0];
            const float py = x[3 * i + 1];
            const float pz = x[3 * i + 2];
            uint32_t h[8]; float w[8];
            prep_level(px, py, pz, r, h, w);
            uint32_t v[8];
            #pragma unroll
            for (int j = 0; j < 8; ++j) v[j] = t16[h[j]];
            const float2 e = accum8(v, w);
            v2f o = {e.x, e.y};
            __builtin_nontemporal_store(o, (v2f*)ws + i);
        }
    }
}

extern __shared__ uint32_t s_dense[];   // DENSE0_N packed half2

__device__ __forceinline__ float2 level0_lds(float px, float py, float pz)
{
    const float sx = px * 30.0f, sy = py * 30.0f, sz = pz * 30.0f;
    const float bx = floorf(sx), by = floorf(sy), bz = floorf(sz);
    const float tx = sx - bx, ty = sy - by, tz = sz - bz;
    const float ux = 1.0f - tx, uy = 1.0f - ty, uz = 1.0f - tz;
    const int ix = (int)bx, iy = (int)by, iz = (int)bz;
    const int lin = (ix * R0 + iy) * R0 + iz;

    float f0 = 0.0f, f1 = 0.0f;
    #pragma unroll
    for (int dx = 0; dx < 2; ++dx) {
        const float wx = dx ? tx : ux;
        #pragma unroll
        for (int dy = 0; dy < 2; ++dy) {
            const float wxy = wx * (dy ? ty : uy);
            const int base = lin + (dx * R0 + dy) * R0;   // z-corners adjacent
            const uint32_t p0 = s_dense[base];
            const uint32_t p1 = s_dense[base + 1];
            const float2 c0 = __half22float2(*(const __half2*)&p0);
            const float2 c1 = __half22float2(*(const __half2*)&p1);
            f0 += wxy * (uz * c0.x + tz * c1.x);
            f1 += wxy * (uz * c0.y + tz * c1.y);
        }
    }
    return make_float2(f0, f1);
}

// Final: level 3 (fp16 gather, 2 pts/thread) + level 0 (LDS) + combine.
__global__ __launch_bounds__(1024) void final16_kernel(
    const float* __restrict__ x, const uint32_t* __restrict__ t16_l3,
    const uint32_t* __restrict__ dense0,
    const float* __restrict__ ws1, const float* __restrict__ ws2,
    float* __restrict__ out, int n)
{
    for (int i = threadIdx.x; i < DENSE0_N; i += 1024)
        s_dense[i] = dense0[i];
    __syncthreads();

    const size_t stride = (size_t)gridDim.x * 1024 * 2;
    for (size_t i0 = ((size_t)blockIdx.x * 1024 + threadIdx.x) * 2;
         i0 < (size_t)n; i0 += stride) {
        if (i0 + 2 <= (size_t)n) {
            const v2f* xv = (const v2f*)(x + 3 * i0);
            const v2f a = __builtin_nontemporal_load(xv);
            const v2f b = __builtin_nontemporal_load(xv + 1);
            const v2f c = __builtin_nontemporal_load(xv + 2);

            uint32_t hA[8], hB[8];
            float wA[8], wB[8];
            prep_level(a.x, a.y, b.x, 512.0f, hA, wA);
            prep_level(b.y, c.x, c.y, 512.0f, hB, wB);

            uint32_t vA[8], vB[8];
            #pragma unroll
            for (int j = 0; j < 8; ++j) vA[j] = t16_l3[hA[j]];
            #pragma unroll
            for (int j = 0; j < 8; ++j) vB[j] = t16_l3[hB[j]];

            // level 0 from LDS while the 16 global gathers are in flight
            const float2 e0A = level0_lds(a.x, a.y, b.x);
            const float2 e0B = level0_lds(b.y, c.x, c.y);

            const v4f w1 = __builtin_nontemporal_load((const v4f*)(ws1 + 2 * i0));
            const v4f w2 = __builtin_nontemporal_load((const v4f*)(ws2 + 2 * i0));

            const float2 e3A = accum8(vA, wA);
            const float2 e3B = accum8(vB, wB);

            v4f* op = (v4f*)(out + 8 * i0);
            v4f oA0 = {e0A.x, e0A.y, w1.x, w1.y};
            v4f oA1 = {w2.x, w2.y, e3A.x, e3A.y};
            v4f oB0 = {e0B.x, e0B.y, w1.z, w1.w};
            v4f oB1 = {w2.z, w2.w, e3B.x, e3B.y};
            __builtin_nontemporal_store(oA0, op);
            __builtin_nontemporal_store(oA1, op + 1);
            __builtin_nontemporal_store(oB0, op + 2);
            __builtin_nontemporal_store(oB1, op + 3);
        } else {
            for (size_t i = i0; i < (size_t)n; ++i) {
                const float px = x[3 * i + 0];
                const float py = x[3 * i + 1];
                const float pz = x[3 * i + 2];
                uint32_t h[8]; float w[8];
                prep_level(px, py, pz, 512.0f, h, w);
                uint32_t v[8];
                #pragma unroll
                for (int j = 0; j < 8; ++j) v[j] = t16_l3[h[j]];
                const float2 e3 = accum8(v, w);
                const float2 e0 = level0_lds(px, py, pz);
                const v2f e1 = *((const v2f*)ws1 + i);
                const v2f e2 = *((const v2f*)ws2 + i);
                v4f* op = (v4f*)(out + 8 * i);
                v4f lo = {e0.x, e0.y, e1.x, e1.y};
                v4f hi = {e2.x, e2.y, e3.x, e3.y};
                __builtin_nontemporal_store(lo, op);
                __builtin_nontemporal_store(hi, op + 1);
            }
        }
    }
}

// Fallback (ws too small / attribute failure): fp32 per-level pass into out.
__global__ __launch_bounds__(256) void pass_direct_kernel(
    const float* __restrict__ x, const float* __restrict__ tables,
    float* __restrict__ out, int li, float r, int n)
{
    const int i = blockIdx.x * blockDim.x + threadIdx.x;
    if (i >= n) return;
    const float px = x[3 * (size_t)i + 0];
    const float py = x[3 * (size_t)i + 1];
    const float pz = x[3 * (size_t)i + 2];
    const float2 e = level_embed_p(px, py, pz, tables, li, r);
    float2* op = (float2*)(out + 8 * (size_t)i + 2 * li);
    *op = e;
}

extern "C" void kernel_launch(void* const* d_in, const int* in_sizes, int n_in,
                              void* d_out, int out_size, void* d_ws, size_t ws_size,
                              hipStream_t stream) {
    const float* x = (const float*)d_in[0];        // [N, 3]
    const float* tables = (const float*)d_in[1];   // [4, 2^19, 2]
    float* out = (float*)d_out;                    // [N, 8]
    const int n = in_sizes[0] / 3;

    // ws layout (bytes):
    //   [0, 6 MB)              : fp16 tables for levels 1,2,3 (2 MB each)
    //   [6 MB, 6 MB + 8n)      : ws1 (float2[n])
    //   [.., + 8n)             : ws2 (float2[n])
    //   [.., + DENSE0_BYTES)   : dense0
    const size_t tab16_bytes = 3 * (size_t)HASHMAP_SIZE * 4;
    const size_t ws_needed = tab16_bytes + 2 * (size_t)n * 8 + DENSE0_BYTES;

    bool fused_ok = (ws_size >= ws_needed);
    if (fused_ok) {
        static int attr_ok = -1;
        if (attr_ok < 0) {
            attr_ok = (hipFuncSetAttribute(
                           reinterpret_cast<const void*>(final16_kernel),
                           hipFuncAttributeMaxDynamicSharedMemorySize,
                           DENSE0_BYTES) == hipSuccess) ? 1 : 0;
        }
        fused_ok = (attr_ok == 1);
    }

    if (fused_ok) {
        char* wsb = (char*)d_ws;
        uint32_t* t16   = (uint32_t*)wsb;                       // levels 1..3
        float*    ws1   = (float*)(wsb + tab16_bytes);
        float*    ws2   = (float*)(wsb + tab16_bytes + (size_t)n * 8);
        uint32_t* dense0 = (uint32_t*)(wsb + tab16_bytes + 2 * (size_t)n * 8);

        convert_fp16<<<(3 * HASHMAP_SIZE + 255) / 256, 256, 0, stream>>>(tables, t16);
        build_dense0<<<(DENSE0_N + 255) / 256, 256, 0, stream>>>(tables, dense0);

        const int block = 256;
        const int grid2 = (n / 2 + block - 1) / block + 1;   // 2 pts/thread
        pass16_kernel<<<grid2, block, 0, stream>>>(x, t16, ws1, 80.0f, n);
        pass16_kernel<<<grid2, block, 0, stream>>>(x, t16 + HASHMAP_SIZE, ws2, 210.0f, n);
        final16_kernel<<<256, 1024, DENSE0_BYTES, stream>>>(
            x, t16 + 2 * HASHMAP_SIZE, dense0, ws1, ws2, out, n);
    } else {
        const float res[N_LEVELS] = {30.0f, 80.0f, 210.0f, 512.0f};
        const int block = 256;
        const int grid = (n + block - 1) / block;
        for (int li = 0; li < N_LEVELS; ++li) {
            pass_direct_kernel<<<grid, block, 0, stream>>>(
                x, tables, out, li, res[li], n);
        }
    }
}

// Round 5
// 254.875 us; speedup vs baseline: 1.2108x; 1.2108x over previous
//
#include <hip/hip_runtime.h>
#include <hip/hip_fp16.h>
#include <stdint.h>

#define LOG2_HASHMAP_SIZE 19
#define HASHMAP_SIZE (1u << LOG2_HASHMAP_SIZE)
#define HASHMAP_MASK (HASHMAP_SIZE - 1u)
#define N_LEVELS 4

// Level 0: res=30 -> 31 vertices/axis. Dense grid fits in LDS as half2.
#define R0 31
#define DENSE0_N (R0 * R0 * R0)        // 29791
#define DENSE0_BYTES (DENSE0_N * 4)    // 119164 B < 160 KiB

// Level 1: res=80 -> 81 vertices/axis. Dense quad-tiled grid in global mem.
// 4 parity copies of 2x2 (y,z) tiles: one 16B load returns all 4 y/z corners
// for one x-slice -> 2 gather requests per point (vs 6 for the hash path).
#define R1 81
#define D1_N (R1 * R1 * R1)            // 531441 scalar vertices (half2 each)
#define QJ 41                          // ceil(81/2) tile slots per axis
#define QUAD1_TILES (4 * R1 * QJ * QJ) // 544644 tiles
#define QUAD1_BYTES ((size_t)QUAD1_TILES * 16)   // 8,714,304 B

// native vector types usable with __builtin_nontemporal_*
typedef float v4f __attribute__((ext_vector_type(4)));
typedef float v2f __attribute__((ext_vector_type(2)));

__device__ __forceinline__ uint32_t hash3(uint32_t ix, uint32_t iy, uint32_t iz) {
    return (ix ^ (iy * 11614769u) ^ (iz * 2654435761u)) & HASHMAP_MASK;
}

__device__ __forceinline__ float2 h2f(uint32_t p) {
    return __half22float2(*(const __half2*)&p);
}
__device__ __forceinline__ uint32_t f2h(float a, float b) {
    const __half2 p = __floats2half2_rn(a, b);
    return *(const uint32_t*)&p;
}

// ---------------- fp32 path (fallback only) ----------------
__device__ __forceinline__ float2 level_embed_p(float px, float py, float pz,
                                                const float* __restrict__ tables,
                                                int li, float r)
{
    const uint32_t P1 = 11614769u;
    const uint32_t P2 = 2654435761u;

    const float sx = px * r, sy = py * r, sz = pz * r;
    const float bx = floorf(sx), by = floorf(sy), bz = floorf(sz);
    const float tx = sx - bx, ty = sy - by, tz = sz - bz;
    const float ux = 1.0f - tx, uy = 1.0f - ty, uz = 1.0f - tz;

    const uint32_t ix = (uint32_t)(int)bx;
    const uint32_t iy = (uint32_t)(int)by;
    const uint32_t iz = (uint32_t)(int)bz;

    const uint32_t hy0 = iy * P1, hy1 = (iy + 1u) * P1;
    const uint32_t hz0 = iz * P2, hz1 = (iz + 1u) * P2;

    uint32_t S[4];
    float W[4];
    S[0] = hy0 ^ hz0;  W[0] = uy * uz;
    S[1] = hy0 ^ hz1;  W[1] = uy * tz;
    S[2] = hy1 ^ hz0;  W[2] = ty * uz;
    S[3] = hy1 ^ hz1;  W[3] = ty * tz;

    const float* tab = tables + (size_t)li * HASHMAP_SIZE * 2;
    const float2* __restrict__ tab2 = (const float2*)tab;

    float f0 = 0.0f, f1 = 0.0f;
    #pragma unroll
    for (int c = 0; c < 4; ++c) {
        const uint32_t h0 = (ix ^ S[c]) & HASHMAP_MASK;
        const uint32_t h1 = ((ix + 1u) ^ S[c]) & HASHMAP_MASK;
        const float2 e0 = tab2[h0];
        const float2 e1 = tab2[h1];
        f0 += W[c] * (ux * e0.x + tx * e1.x);
        f1 += W[c] * (ux * e0.y + tx * e1.y);
    }
    return make_float2(f0, f1);
}

// ---------------- fp16 hash gather (divergent even/odd — measured fastest:
// avg 6 gather requests per point-level; request rate is the HW ceiling) ----
__device__ __forceinline__ float2 level_embed_h16(float px, float py, float pz,
                                                  const uint32_t* __restrict__ t16,
                                                  float r)
{
    const uint32_t P1 = 11614769u;
    const uint32_t P2 = 2654435761u;

    const float sx = px * r, sy = py * r, sz = pz * r;
    const float bx = floorf(sx), by = floorf(sy), bz = floorf(sz);
    const float tx = sx - bx, ty = sy - by, tz = sz - bz;
    const float ux = 1.0f - tx, uy = 1.0f - ty, uz = 1.0f - tz;

    const uint32_t ix = (uint32_t)(int)bx;
    const uint32_t iy = (uint32_t)(int)by;
    const uint32_t iz = (uint32_t)(int)bz;

    const uint32_t hy0 = iy * P1, hy1 = (iy + 1u) * P1;
    const uint32_t hz0 = iz * P2, hz1 = (iz + 1u) * P2;

    uint32_t S[4];
    float W[4];
    S[0] = hy0 ^ hz0;  W[0] = uy * uz;
    S[1] = hy0 ^ hz1;  W[1] = uy * tz;
    S[2] = hy1 ^ hz0;  W[2] = ty * uz;
    S[3] = hy1 ^ hz1;  W[3] = ty * tz;

    float f0 = 0.0f, f1 = 0.0f;
    if ((ix & 1u) == 0u) {
        // even ix: one aligned 8B load covers both x-corners
        #pragma unroll
        for (int c = 0; c < 4; ++c) {
            const uint32_t h0 = (ix ^ S[c]) & HASHMAP_MASK;
            const uint2 v = ((const uint2*)t16)[h0 >> 1];
            const uint32_t p0 = (h0 & 1u) ? v.y : v.x;
            const uint32_t p1 = (h0 & 1u) ? v.x : v.y;
            const float2 e0 = h2f(p0);
            const float2 e1 = h2f(p1);
            f0 += W[c] * (ux * e0.x + tx * e1.x);
            f1 += W[c] * (ux * e0.y + tx * e1.y);
        }
    } else {
        #pragma unroll
        for (int c = 0; c < 4; ++c) {
            const uint32_t h0 = (ix ^ S[c]) & HASHMAP_MASK;
            const uint32_t h1 = ((ix + 1u) ^ S[c]) & HASHMAP_MASK;
            const float2 e0 = h2f(t16[h0]);
            const float2 e1 = h2f(t16[h1]);
            f0 += W[c] * (ux * e0.x + tx * e1.x);
            f1 += W[c] * (ux * e0.y + tx * e1.y);
        }
    }
    return make_float2(f0, f1);
}

// ---------------- setup kernels ----------------
// Pack levels 2,3 tables to fp16 (half2 per entry).
__global__ __launch_bounds__(256) void convert_fp16(
    const float* __restrict__ tables, uint32_t* __restrict__ t16)
{
    const int i = blockIdx.x * blockDim.x + threadIdx.x;
    if (i >= 2 * (int)HASHMAP_SIZE) return;
    const float2 e = ((const float2*)tables)[2 * HASHMAP_SIZE + i];  // levels 2,3
    t16[i] = f2h(e.x, e.y);
}

// Level-0 dense vertex grid as half2 (for LDS staging in final).
__global__ __launch_bounds__(256) void build_dense0(
    const float* __restrict__ tables, uint32_t* __restrict__ dense0)
{
    const int v = blockIdx.x * blockDim.x + threadIdx.x;
    if (v >= DENSE0_N) return;
    const int vx = v / (R0 * R0);
    const int rem = v - vx * (R0 * R0);
    const int vy = rem / R0;
    const int vz = rem - vy * R0;
    const uint32_t h = hash3((uint32_t)vx, (uint32_t)vy, (uint32_t)vz);
    const float2 e = ((const float2*)tables)[h];   // level-0 table at offset 0
    dense0[v] = f2h(e.x, e.y);
}

// Level-1 scalar dense grid (hash applied once per vertex: 531K gathers).
__global__ __launch_bounds__(256) void build_dense1(
    const float* __restrict__ tables, uint32_t* __restrict__ d1)
{
    const int v = blockIdx.x * blockDim.x + threadIdx.x;
    if (v >= D1_N) return;
    const int vx = v / (R1 * R1);
    const int rem = v - vx * (R1 * R1);
    const int vy = rem / R1;
    const int vz = rem - vy * R1;
    const uint32_t h = hash3((uint32_t)vx, (uint32_t)vy, (uint32_t)vz);
    const float2 e = ((const float2*)tables)[HASHMAP_SIZE + h];   // level 1
    d1[v] = f2h(e.x, e.y);
}

// Expand scalar grid into 4 parity copies of 2x2 (y,z) quad tiles.
// Local/streaming reads from the 2.1 MB d1 (L2-resident) — cheap.
__global__ __launch_bounds__(256) void expand_quad1(
    const uint32_t* __restrict__ d1, uint4* __restrict__ quad)
{
    const int t = blockIdx.x * blockDim.x + threadIdx.x;
    if (t >= QUAD1_TILES) return;
    const int per_copy = R1 * QJ * QJ;
    const int c  = t / per_copy;
    int rem = t - c * per_copy;
    const int vx = rem / (QJ * QJ);
    rem -= vx * (QJ * QJ);
    const int jy = rem / QJ;
    const int jz = rem - jy * QJ;
    const int py = c >> 1, pz = c & 1;
    int y0 = 2 * jy + py, z0 = 2 * jz + pz;
    int y1 = y0 + 1,      z1 = z0 + 1;
    y0 = min(y0, R1 - 1); y1 = min(y1, R1 - 1);   // clamp: padded slots unused
    z0 = min(z0, R1 - 1); z1 = min(z1, R1 - 1);
    const uint32_t* base = d1 + (size_t)vx * R1 * R1;
    uint4 q;
    q.x = base[y0 * R1 + z0];
    q.y = base[y0 * R1 + z1];
    q.z = base[y1 * R1 + z0];
    q.w = base[y1 * R1 + z1];
    quad[t] = q;
}

// ---------------- pass kernels ----------------
// Level 1 via quad tiles: exactly 2 gather requests per point.
__global__ __launch_bounds__(256) void pass1_quad(
    const float* __restrict__ x, const uint4* __restrict__ quad,
    uint32_t* __restrict__ ws, int n)
{
    const int i = blockIdx.x * blockDim.x + threadIdx.x;
    if (i >= n) return;
    const float px = __builtin_nontemporal_load(x + 3 * (size_t)i + 0);
    const float py = __builtin_nontemporal_load(x + 3 * (size_t)i + 1);
    const float pz = __builtin_nontemporal_load(x + 3 * (size_t)i + 2);

    const float sx = px * 80.0f, sy = py * 80.0f, sz = pz * 80.0f;
    const float bx = floorf(sx), by = floorf(sy), bz = floorf(sz);
    const float tx = sx - bx, ty = sy - by, tz = sz - bz;
    const float ux = 1.0f - tx, uy = 1.0f - ty, uz = 1.0f - tz;
    const int ix = (int)bx, iy = (int)by, iz = (int)bz;

    const int c = ((iy & 1) << 1) | (iz & 1);
    const size_t base = (((size_t)c * R1 + ix) * QJ + (iy >> 1)) * QJ + (iz >> 1);
    const uint4 q0 = quad[base];             // x-corner ix
    const uint4 q1 = quad[base + QJ * QJ];   // x-corner ix+1

    const float w00 = uy * uz, w01 = uy * tz, w10 = ty * uz, w11 = ty * tz;
    const float2 a0 = h2f(q0.x), a1 = h2f(q0.y), a2 = h2f(q0.z), a3 = h2f(q0.w);
    const float2 b0 = h2f(q1.x), b1 = h2f(q1.y), b2 = h2f(q1.z), b3 = h2f(q1.w);

    const float f0 = ux * (w00 * a0.x + w01 * a1.x + w10 * a2.x + w11 * a3.x)
                   + tx * (w00 * b0.x + w01 * b1.x + w10 * b2.x + w11 * b3.x);
    const float f1 = ux * (w00 * a0.y + w01 * a1.y + w10 * a2.y + w11 * a3.y)
                   + tx * (w00 * b0.y + w01 * b1.y + w10 * b2.y + w11 * b3.y);

    __builtin_nontemporal_store(f2h(f0, f1), ws + i);
}

// Level 2 via fp16 hash table (2 MB, L2-resident).
__global__ __launch_bounds__(256) void pass2_hash(
    const float* __restrict__ x, const uint32_t* __restrict__ t16,
    uint32_t* __restrict__ ws, int n)
{
    const int i = blockIdx.x * blockDim.x + threadIdx.x;
    if (i >= n) return;
    const float px = __builtin_nontemporal_load(x + 3 * (size_t)i + 0);
    const float py = __builtin_nontemporal_load(x + 3 * (size_t)i + 1);
    const float pz = __builtin_nontemporal_load(x + 3 * (size_t)i + 2);
    const float2 e = level_embed_h16(px, py, pz, t16, 210.0f);
    __builtin_nontemporal_store(f2h(e.x, e.y), ws + i);
}

extern __shared__ uint32_t s_dense[];   // DENSE0_N packed half2

// Final: level 3 (fp16 hash gather) + level 0 (LDS) + combine ws1/ws2.
__global__ __launch_bounds__(1024) void final16_kernel(
    const float* __restrict__ x, const uint32_t* __restrict__ t16_l3,
    const uint32_t* __restrict__ dense0,
    const uint32_t* __restrict__ ws1, const uint32_t* __restrict__ ws2,
    float* __restrict__ out, int n)
{
    for (int i = threadIdx.x; i < DENSE0_N; i += 1024)
        s_dense[i] = dense0[i];
    __syncthreads();

    const size_t stride = (size_t)gridDim.x * 1024;
    for (size_t i = (size_t)blockIdx.x * 1024 + threadIdx.x; i < (size_t)n; i += stride) {
        const float px = __builtin_nontemporal_load(x + 3 * i + 0);
        const float py = __builtin_nontemporal_load(x + 3 * i + 1);
        const float pz = __builtin_nontemporal_load(x + 3 * i + 2);

        // level 3: global fp16 gathers (long latency; issue first)
        const float2 e3 = level_embed_h16(px, py, pz, t16_l3, 512.0f);

        // level 0 from LDS dense grid
        const float sx = px * 30.0f, sy = py * 30.0f, sz = pz * 30.0f;
        const float bx = floorf(sx), by = floorf(sy), bz = floorf(sz);
        const float tx = sx - bx, ty = sy - by, tz = sz - bz;
        const float uxv = 1.0f - tx, uyv = 1.0f - ty, uzv = 1.0f - tz;
        const int ix = (int)bx, iy = (int)by, iz = (int)bz;
        const int lin = (ix * R0 + iy) * R0 + iz;

        float f0 = 0.0f, f1 = 0.0f;
        #pragma unroll
        for (int dx = 0; dx < 2; ++dx) {
            const float wx = dx ? tx : uxv;
            #pragma unroll
            for (int dy = 0; dy < 2; ++dy) {
                const float wxy = wx * (dy ? ty : uyv);
                const int base = lin + (dx * R0 + dy) * R0;   // z-corners adjacent
                const float2 c0 = h2f(s_dense[base]);
                const float2 c1 = h2f(s_dense[base + 1]);
                f0 += wxy * (uzv * c0.x + tz * c1.x);
                f1 += wxy * (uzv * c0.y + tz * c1.y);
            }
        }

        const float2 e1 = h2f(__builtin_nontemporal_load(ws1 + i));
        const float2 e2 = h2f(__builtin_nontemporal_load(ws2 + i));

        v4f* op = (v4f*)(out + 8 * i);
        v4f lo = {f0, f1, e1.x, e1.y};
        v4f hi = {e2.x, e2.y, e3.x, e3.y};
        __builtin_nontemporal_store(lo, op);
        __builtin_nontemporal_store(hi, op + 1);
    }
}

// Fallback (ws too small / attribute failure): fp32 per-level pass into out.
__global__ __launch_bounds__(256) void pass_direct_kernel(
    const float* __restrict__ x, const float* __restrict__ tables,
    float* __restrict__ out, int li, float r, int n)
{
    const int i = blockIdx.x * blockDim.x + threadIdx.x;
    if (i >= n) return;
    const float px = x[3 * (size_t)i + 0];
    const float py = x[3 * (size_t)i + 1];
    const float pz = x[3 * (size_t)i + 2];
    const float2 e = level_embed_p(px, py, pz, tables, li, r);
    float2* op = (float2*)(out + 8 * (size_t)i + 2 * li);
    *op = e;
}

extern "C" void kernel_launch(void* const* d_in, const int* in_sizes, int n_in,
                              void* d_out, int out_size, void* d_ws, size_t ws_size,
                              hipStream_t stream) {
    const float* x = (const float*)d_in[0];        // [N, 3]
    const float* tables = (const float*)d_in[1];   // [4, 2^19, 2]
    float* out = (float*)d_out;                    // [N, 8]
    const int n = in_sizes[0] / 3;

    // ws layout (bytes), all segments 16B-aligned where needed:
    //   [0, 4MB)        : t16 for levels 2,3 (2 MB each)
    //   [+QUAD1_BYTES)  : level-1 quad tiles (8.71 MB)
    //   [+D1_N*4)       : level-1 scalar dense grid (2.13 MB)
    //   [+DENSE0_BYTES) : level-0 dense grid
    //   [+4n)           : ws1 (half2[n])
    //   [+4n)           : ws2 (half2[n])
    const size_t t16_bytes = 2 * (size_t)HASHMAP_SIZE * 4;
    const size_t off_quad  = t16_bytes;
    const size_t off_d1    = off_quad + QUAD1_BYTES;
    const size_t off_d0    = off_d1 + (size_t)D1_N * 4;
    const size_t off_ws1   = off_d0 + DENSE0_BYTES;
    const size_t off_ws2   = off_ws1 + (size_t)n * 4;
    const size_t ws_needed = off_ws2 + (size_t)n * 4;

    bool fused_ok = (ws_size >= ws_needed);
    if (fused_ok) {
        static int attr_ok = -1;
        if (attr_ok < 0) {
            attr_ok = (hipFuncSetAttribute(
                           reinterpret_cast<const void*>(final16_kernel),
                           hipFuncAttributeMaxDynamicSharedMemorySize,
                           DENSE0_BYTES) == hipSuccess) ? 1 : 0;
        }
        fused_ok = (attr_ok == 1);
    }

    if (fused_ok) {
        char* wsb = (char*)d_ws;
        uint32_t* t16    = (uint32_t*)wsb;
        uint4*    quad   = (uint4*)(wsb + off_quad);
        uint32_t* d1     = (uint32_t*)(wsb + off_d1);
        uint32_t* dense0 = (uint32_t*)(wsb + off_d0);
        uint32_t* ws1    = (uint32_t*)(wsb + off_ws1);
        uint32_t* ws2    = (uint32_t*)(wsb + off_ws2);

        convert_fp16<<<(2 * HASHMAP_SIZE + 255) / 256, 256, 0, stream>>>(tables, t16);
        build_dense0<<<(DENSE0_N + 255) / 256, 256, 0, stream>>>(tables, dense0);
        build_dense1<<<(D1_N + 255) / 256, 256, 0, stream>>>(tables, d1);
        expand_quad1<<<(QUAD1_TILES + 255) / 256, 256, 0, stream>>>(d1, quad);

        const int block = 256;
        const int grid = (n + block - 1) / block;
        pass1_quad<<<grid, block, 0, stream>>>(x, quad, ws1, n);
        pass2_hash<<<grid, block, 0, stream>>>(x, t16, ws2, n);
        final16_kernel<<<256, 1024, DENSE0_BYTES, stream>>>(
            x, t16 + HASHMAP_SIZE, dense0, ws1, ws2, out, n);
    } else {
        const float res[N_LEVELS] = {30.0f, 80.0f, 210.0f, 512.0f};
        const int block = 256;
        const int grid = (n + block - 1) / block;
        for (int li = 0; li < N_LEVELS; ++li) {
            pass_direct_kernel<<<grid, block, 0, stream>>>(
                x, tables, out, li, res[li], n);
        }
    }
}